// Round 1
// baseline (289.255 us; speedup 1.0000x reference)
//
#include <hip/hip_runtime.h>
#include <stdint.h>

// GAT encoder, 2 layers. B=128, K=512, Fin=224, H1=64, H2=32.
// Pipeline: bitmask(adj) -> prep(W->bf16) -> gemm1(+fs/fd) -> attn1 -> gemm2(+fs/fd) -> attn2.
// Softmax trick: att = exp(e-8)*mask / sum(exp(e-8)*mask)  (exact, no max pass; logits bounded ~ +-7)

#define B_   128
#define K_   512
#define FIN  224
#define H1   64
#define H2   32

typedef float    f32x4 __attribute__((ext_vector_type(4)));
typedef short    s16x8 __attribute__((ext_vector_type(8)));
typedef unsigned short u16;

__device__ __forceinline__ u16 f2bf(float f){              // RNE float->bf16
  uint32_t u = __float_as_uint(f);
  u += 0x7FFFu + ((u >> 16) & 1u);
  return (u16)(u >> 16);
}
__device__ __forceinline__ float bf2f(u16 h){ return __uint_as_float(((uint32_t)h) << 16); }

// ---------------- adj -> bitmask (1 bit per edge) ----------------
__global__ __launch_bounds__(256) void k_bitmask(const int* __restrict__ adj, uint32_t* __restrict__ bits){
  size_t w = (size_t)blockIdx.x * 256 + threadIdx.x;   // word index; grid covers B*K*16 exactly
  const int4* p = reinterpret_cast<const int4*>(adj) + w * 8;
  uint32_t m = 0;
#pragma unroll
  for (int c = 0; c < 8; ++c){
    int4 v = p[c];
    m |= (v.x != 0 ? 1u : 0u) << (4*c + 0);
    m |= (v.y != 0 ? 1u : 0u) << (4*c + 1);
    m |= (v.z != 0 ? 1u : 0u) << (4*c + 2);
    m |= (v.w != 0 ? 1u : 0u) << (4*c + 3);
  }
  bits[w] = m;
}

// ---------------- W1/W2 -> bf16 ----------------
__global__ __launch_bounds__(256) void k_prep(const float* __restrict__ W1, const float* __restrict__ W2,
                                              u16* __restrict__ W1b, u16* __restrict__ W2b){
  int t = blockIdx.x * 256 + threadIdx.x;
  if (t < FIN * H1) W1b[t] = f2bf(W1[t]);
  else { int u = t - FIN * H1; if (u < H1 * H2) W2b[u] = f2bf(W2[u]); }
}

// ---------------- GEMM: Wh = A @ W  (+ fused fs/fd = Wh . a_src/a_dst) ----------------
// block: 256 thr = 4 waves, 64 output rows (16/wave), NO output cols.
// MFMA 16x16x32 bf16. A-frag: row=lane&15, k=8*(lane>>4)+e. B-frag: col=lane&15, same k map.
template<int KD, int NO, bool AF32>
__global__ __launch_bounds__(256) void k_gemm(const void* __restrict__ Ain, const u16* __restrict__ Wb,
                                              const float* __restrict__ avec,
                                              u16* __restrict__ Whout, float* __restrict__ fs, float* __restrict__ fd){
  __shared__ u16 xs[64 * 40];        // A tile [64 rows][32 k], row stride 40 bf16 (pad -> 2-way banks)
  __shared__ u16 wtT[NO * 56];       // W tile transposed [o][k], row stride 56 bf16 (112 B, 16B-aligned)
  const int tid  = threadIdx.x;
  const int wid  = tid >> 6, lane = tid & 63;
  const int g    = lane >> 4, lr = lane & 15;
  const size_t row0 = (size_t)blockIdx.x * 64;

  f32x4 acc[NO / 16];
#pragma unroll
  for (int c = 0; c < NO/16; ++c) acc[c] = (f32x4){0.f, 0.f, 0.f, 0.f};

  const int r_st = tid >> 2, c_st = tid & 3;      // A staging: 8 elems each
  const int j_w  = tid & 31, o0_w = (tid >> 5) * 8; // W staging: 8 o-elems of row j

  for (int s = 0; s < KD/32; ++s){
    const int k0 = s * 32;
    __syncthreads();
    // stage A tile (convert f32->bf16 if needed)
    if (AF32){
      const float* A = (const float*)Ain;
      const float* src = A + (row0 + r_st) * KD + k0 + c_st * 8;
      float4 v0 = *(const float4*)(src);
      float4 v1 = *(const float4*)(src + 4);
      uint4 pk;
      pk.x = (uint32_t)f2bf(v0.x) | ((uint32_t)f2bf(v0.y) << 16);
      pk.y = (uint32_t)f2bf(v0.z) | ((uint32_t)f2bf(v0.w) << 16);
      pk.z = (uint32_t)f2bf(v1.x) | ((uint32_t)f2bf(v1.y) << 16);
      pk.w = (uint32_t)f2bf(v1.z) | ((uint32_t)f2bf(v1.w) << 16);
      *(uint4*)&xs[r_st * 40 + c_st * 8] = pk;
    } else {
      const u16* A = (const u16*)Ain;
      uint4 v = *(const uint4*)(A + (row0 + r_st) * KD + k0 + c_st * 8);
      *(uint4*)&xs[r_st * 40 + c_st * 8] = v;
    }
    // stage W tile transposed (k-slice rows k0..k0+31)
    if (tid < NO * 4){
      uint4 v = *(const uint4*)(Wb + (size_t)(k0 + j_w) * NO + o0_w);
      u16 h[8] = { (u16)(v.x & 0xFFFF), (u16)(v.x >> 16), (u16)(v.y & 0xFFFF), (u16)(v.y >> 16),
                   (u16)(v.z & 0xFFFF), (u16)(v.z >> 16), (u16)(v.w & 0xFFFF), (u16)(v.w >> 16) };
#pragma unroll
      for (int e = 0; e < 8; ++e) wtT[(o0_w + e) * 56 + j_w] = h[e];
    }
    __syncthreads();
    const s16x8 af = *(const s16x8*)&xs[(16 * wid + lr) * 40 + 8 * g];
#pragma unroll
    for (int c = 0; c < NO/16; ++c){
      const s16x8 bf = *(const s16x8*)&wtT[(16 * c + lr) * 56 + 8 * g];
      acc[c] = __builtin_amdgcn_mfma_f32_16x16x32_bf16(af, bf, acc[c], 0, 0, 0);
    }
  }

  // epilogue: write Wh bf16, fused fs/fd
  float fsp[4] = {0.f,0.f,0.f,0.f}, fdp[4] = {0.f,0.f,0.f,0.f};
#pragma unroll
  for (int c = 0; c < NO/16; ++c){
    float as = avec[16 * c + lr], ad = avec[NO + 16 * c + lr];
#pragma unroll
    for (int r = 0; r < 4; ++r){
      fsp[r] += acc[c][r] * as;
      fdp[r] += acc[c][r] * ad;
      size_t row = row0 + 16 * wid + 4 * g + r;
      Whout[row * NO + 16 * c + lr] = f2bf(acc[c][r]);
    }
  }
#pragma unroll
  for (int m = 1; m < 16; m <<= 1){
#pragma unroll
    for (int r = 0; r < 4; ++r){ fsp[r] += __shfl_xor(fsp[r], m); fdp[r] += __shfl_xor(fdp[r], m); }
  }
  if (lr == 0){
#pragma unroll
    for (int r = 0; r < 4; ++r){
      size_t row = row0 + 16 * wid + 4 * g + r;
      fs[row] = fsp[r]; fd[row] = fdp[r];
    }
  }
}

// ---------------- fused masked-softmax attention:  out = elu( (P @ Wh) / rowsum(P) ) ----------------
// block: 256 thr = 4 waves; 64 P-rows (16/wave) of one batch; j tiled by 32 (16 steps).
// P computed per-lane directly in MFMA A-fragment layout; Wh tile staged transposed in LDS.
template<int NO, bool OUTBF>
__global__ __launch_bounds__(256) void k_attn(const u16* __restrict__ Wh, const float* __restrict__ fsv,
                                              const float* __restrict__ fdv, const uint32_t* __restrict__ bits,
                                              void* __restrict__ outp){
  __shared__ u16  wtT[NO * 56];
  __shared__ float fd_s[K_];
  __shared__ float ls_s[64];
  const int tid = threadIdx.x;
  const int wid = tid >> 6, lane = tid & 63;
  const int g   = lane >> 4, lr = lane & 15;
  const int b   = blockIdx.x >> 3;
  const int i0  = (blockIdx.x & 7) * 64;
  const int prow = i0 + 16 * wid + lr;                  // this lane's P row
  const float fsr = fsv[(size_t)b * K_ + prow];
  fd_s[tid]       = fdv[(size_t)b * K_ + tid];
  fd_s[256 + tid] = fdv[(size_t)b * K_ + 256 + tid];

  f32x4 acc[NO / 16];
#pragma unroll
  for (int c = 0; c < NO/16; ++c) acc[c] = (f32x4){0.f, 0.f, 0.f, 0.f};
  float lsum = 0.f;

  const uint32_t* brow = bits + ((size_t)b * K_ + prow) * 16;
  const int j_w = tid & 31, o0_w = (tid >> 5) * 8;

  for (int st = 0; st < 16; ++st){
    __syncthreads();
    // stage Wh tile rows st*32..+31, transposed
    if (tid < NO * 4){
      uint4 v = *(const uint4*)(Wh + ((size_t)b * K_ + st * 32 + j_w) * NO + o0_w);
      u16 h[8] = { (u16)(v.x & 0xFFFF), (u16)(v.x >> 16), (u16)(v.y & 0xFFFF), (u16)(v.y >> 16),
                   (u16)(v.z & 0xFFFF), (u16)(v.z >> 16), (u16)(v.w & 0xFFFF), (u16)(v.w >> 16) };
#pragma unroll
      for (int e = 0; e < 8; ++e) wtT[(o0_w + e) * 56 + j_w] = h[e];
    }
    // compute this lane's 8 P values (j = st*32 + 8*g + e)
    uint32_t bw   = brow[st];
    uint32_t byte = (bw >> (8 * g)) & 0xFFu;
    float4 fd0 = *(const float4*)&fd_s[st * 32 + 8 * g];
    float4 fd1 = *(const float4*)&fd_s[st * 32 + 8 * g + 4];
    float pv[8] = { fd0.x, fd0.y, fd0.z, fd0.w, fd1.x, fd1.y, fd1.z, fd1.w };
    u16 ph[8];
    float lacc = 0.f;
#pragma unroll
    for (int e = 0; e < 8; ++e){
      float sc = fsr + pv[e];
      sc = fmaxf(sc, 0.2f * sc);                 // leaky_relu
      float pe = __expf(sc - 8.0f);              // shifted exp (exact softmax up to common factor)
      pe = ((byte >> e) & 1u) ? pe : 0.f;        // mask
      u16 h = f2bf(pe);
      ph[e] = h;
      lacc += bf2f(h);                           // rowsum of the *rounded* p -> consistent normalization
    }
    lsum += lacc;
    s16x8 af;
    af[0]=(short)ph[0]; af[1]=(short)ph[1]; af[2]=(short)ph[2]; af[3]=(short)ph[3];
    af[4]=(short)ph[4]; af[5]=(short)ph[5]; af[6]=(short)ph[6]; af[7]=(short)ph[7];
    __syncthreads();
#pragma unroll
    for (int c = 0; c < NO/16; ++c){
      const s16x8 bf = *(const s16x8*)&wtT[(16 * c + lr) * 56 + 8 * g];
      acc[c] = __builtin_amdgcn_mfma_f32_16x16x32_bf16(af, bf, acc[c], 0, 0, 0);
    }
  }

  // rowsum reduce across the 4 k-group lanes of each row
  lsum += __shfl_xor(lsum, 16);
  lsum += __shfl_xor(lsum, 32);
  if (g == 0) ls_s[16 * wid + lr] = lsum;
  __syncthreads();

  float inv[4];
#pragma unroll
  for (int r = 0; r < 4; ++r) inv[r] = 1.0f / ls_s[16 * wid + 4 * g + r];
#pragma unroll
  for (int c = 0; c < NO/16; ++c){
#pragma unroll
    for (int r = 0; r < 4; ++r){
      float v = acc[c][r] * inv[r];
      v = v > 0.f ? v : (__expf(v) - 1.0f);      // elu
      size_t row = (size_t)b * K_ + i0 + 16 * wid + 4 * g + r;
      if (OUTBF) ((u16*)outp)[row * NO + 16 * c + lr] = f2bf(v);
      else       ((float*)outp)[row * NO + 16 * c + lr] = v;
    }
  }
}

extern "C" void kernel_launch(void* const* d_in, const int* in_sizes, int n_in,
                              void* d_out, int out_size, void* d_ws, size_t ws_size,
                              hipStream_t stream){
  const float* x   = (const float*)d_in[0];
  const int*   adj = (const int*)  d_in[1];
  const float* W1  = (const float*)d_in[2];
  const float* a1  = (const float*)d_in[3];
  const float* W2  = (const float*)d_in[4];
  const float* a2  = (const float*)d_in[5];
  float* out = (float*)d_out;

  char* ws = (char*)d_ws;                       // total use: ~26.25 MB
  u16*      Wh1  = (u16*)     (ws);             // B*K*64 bf16  (8 MB)
  u16*      h1   = (u16*)     (ws + 8388608);   // B*K*64 bf16  (8 MB)
  u16*      Wh2  = (u16*)     (ws + 16777216);  // B*K*32 bf16  (4 MB)
  uint32_t* bits = (uint32_t*)(ws + 20971520);  // B*K*16 words (4 MB)
  float*    fs1  = (float*)   (ws + 25165824);
  float*    fd1  = (float*)   (ws + 25427968);
  float*    fs2  = (float*)   (ws + 25690112);
  float*    fd2  = (float*)   (ws + 25952256);
  u16*      W1b  = (u16*)     (ws + 26214400);
  u16*      W2b  = (u16*)     (ws + 26243072);

  k_bitmask<<<dim3(4096), dim3(256), 0, stream>>>(adj, bits);
  k_prep   <<<dim3(64),   dim3(256), 0, stream>>>(W1, W2, W1b, W2b);
  k_gemm<FIN, H1, true >  <<<dim3(1024), dim3(256), 0, stream>>>((const void*)x,  W1b, a1, Wh1, fs1, fd1);
  k_attn<H1, true >       <<<dim3(1024), dim3(256), 0, stream>>>(Wh1, fs1, fd1, bits, (void*)h1);
  k_gemm<H1,  H2, false>  <<<dim3(1024), dim3(256), 0, stream>>>((const void*)h1, W2b, a2, Wh2, fs2, fd2);
  k_attn<H2, false>       <<<dim3(1024), dim3(256), 0, stream>>>(Wh2, fs2, fd2, bits, (void*)out);
}